// Round 3
// baseline (37386.719 us; speedup 1.0000x reference)
//
#include <hip/hip_runtime.h>

typedef unsigned short u16;
typedef unsigned int   u32;
typedef unsigned long long u64;

#define Bb   32
#define Tt   256
#define Ss   512
#define Hh   512
#define G4H  2048
#define NBLK 256

// ---- dtype-polymorphic load/store: F32 ? fp32 : bf16 ------------------------
template<bool F32>
__device__ __forceinline__ float ldin(const void* p, size_t i) {
    if constexpr (F32) {
        return ((const float*)p)[i];
    } else {
        u32 v = ((u32)((const u16*)p)[i]) << 16;
        return __uint_as_float(v);
    }
}
template<bool F32>
__device__ __forceinline__ void stout(void* p, size_t i, float f) {
    if constexpr (F32) {
        ((float*)p)[i] = f;
    } else {
        u32 x = __float_as_uint(f);
        u32 r = x + 0x7fffu + ((x >> 16) & 1u);   // RNE
        ((u16*)p)[i] = (u16)(r >> 16);
    }
}
template<bool F32>
__device__ __forceinline__ float4 ld4(const void* p, size_t i) {
    if constexpr (F32) {
        return *(const float4*)((const float*)p + i);
    } else {
        ushort4 u = *(const ushort4*)((const u16*)p + i);
        float4 f;
        f.x = __uint_as_float((u32)u.x << 16);
        f.y = __uint_as_float((u32)u.y << 16);
        f.z = __uint_as_float((u32)u.z << 16);
        f.w = __uint_as_float((u32)u.w << 16);
        return f;
    }
}

// ---- cache-bypassing (coherence-point) accessors for mutable ws state -------
__device__ __forceinline__ float ldb(const float* p) {
    return __hip_atomic_load(p, __ATOMIC_RELAXED, __HIP_MEMORY_SCOPE_AGENT);
}
__device__ __forceinline__ void stb(float* p, float v) {
    __hip_atomic_store(p, v, __ATOMIC_RELAXED, __HIP_MEMORY_SCOPE_AGENT);
}
__device__ __forceinline__ float2 ldb2(const float* p) {
    u64 v = __hip_atomic_load((const u64*)p, __ATOMIC_RELAXED, __HIP_MEMORY_SCOPE_AGENT);
    float2 r;
    r.x = __uint_as_float((u32)v);
    r.y = __uint_as_float((u32)(v >> 32));
    return r;
}

// ---- light grid barrier: no cache maintenance, relaxed atomics only ---------
__device__ __forceinline__ void gbar(int* cnt, int* gen) {
    __syncthreads();
    if (threadIdx.x == 0) {
        int g = __hip_atomic_load(gen, __ATOMIC_RELAXED, __HIP_MEMORY_SCOPE_AGENT);
        if (__hip_atomic_fetch_add(cnt, 1, __ATOMIC_RELAXED, __HIP_MEMORY_SCOPE_AGENT) == NBLK - 1) {
            __hip_atomic_store(cnt, 0, __ATOMIC_RELAXED, __HIP_MEMORY_SCOPE_AGENT);
            asm volatile("s_waitcnt vmcnt(0)" ::: "memory");   // cnt reset lands before gen bump
            __hip_atomic_store(gen, g + 1, __ATOMIC_RELAXED, __HIP_MEMORY_SCOPE_AGENT);
        } else {
            while (__hip_atomic_load(gen, __ATOMIC_RELAXED, __HIP_MEMORY_SCOPE_AGENT) == g)
                __builtin_amdgcn_s_sleep(1);
        }
    }
    __syncthreads();
}

// ---------------------------------------------------------------------------
// K0: dtype detector + barrier-state init
// ---------------------------------------------------------------------------
__global__ __launch_bounds__(256) void k_detect(const void* ctx, int* flag, int* cnt, int* gen) {
    __shared__ int c_sh;
    if (threadIdx.x == 0) c_sh = 0;
    __syncthreads();
    const u16* p = (const u16*)ctx;
    int c = 0;
    for (int i = threadIdx.x; i < 16384; i += 256) {
        int e = (p[i] >> 7) & 0xFF;
        if (e >= 0xC8) c++;
    }
    atomicAdd(&c_sh, c);
    __syncthreads();
    if (threadIdx.x == 0) {
        *flag = (c_sh > 64) ? 1 : 0;
        *cnt = 0;
        *gen = 0;
    }
}

// ---------------------------------------------------------------------------
// K0b: one-time ctx -> bf16 side-buffer (halves the dominant per-ts L2 stream
// so each XCD's slice becomes L2-resident). Copy-through if already bf16.
// ---------------------------------------------------------------------------
__device__ __forceinline__ u32 pack2bf(float a, float b) {
    u32 xa = __float_as_uint(a), xb = __float_as_uint(b);
    u32 ra = (xa + 0x7fffu + ((xa >> 16) & 1u)) >> 16;
    u32 rb = (xb + 0x7fffu + ((xb >> 16) & 1u)) & 0xffff0000u;
    return ra | rb;
}
__global__ __launch_bounds__(256) void k_cvt(const int* flag, const void* ctx, u16* ctxb) {
    const size_t i = ((size_t)blockIdx.x * 256 + threadIdx.x) * 8;   // 8.39M elems / 8
    if (*flag) {
        const float* s = (const float*)ctx + i;
        float4 v0 = *(const float4*)(s);
        float4 v1 = *(const float4*)(s + 4);
        uint4 o;
        o.x = pack2bf(v0.x, v0.y);
        o.y = pack2bf(v0.z, v0.w);
        o.z = pack2bf(v1.x, v1.y);
        o.w = pack2bf(v1.z, v1.w);
        *(uint4*)(ctxb + i) = o;
    } else {
        *(uint4*)(ctxb + i) = *(const uint4*)((const u16*)ctx + i);
    }
}

// ===========================================================================
// Fused persistent kernel: 256 blocks x 512 threads, custom light barriers
// ===========================================================================
struct KP {
    const void *input, *h0, *c0, *ctx, *Wi, *bi, *Wh, *bhp, *Wa_in, *Wa_out;
    const void* ctxs;      // ctx for P3: bf16 side-buffer if ctxB16, else original
    int ctxB16;
    void* out;
    const int* flag;
    int *cnt, *gen;
    float *h_ws, *c_ws, *hy_ws, *tgt_ws, *wc_ws, *e_ws, *esum_ws;
};

#define SMEM_FLOATS 33856   // max(P1: 16*1028+8*16*17+256, P3: 64*520+512+64)

template<bool F32>
__device__ void run_all(const KP& p, float* smem) {
    const int bid = blockIdx.x;
    const int tid = threadIdx.x;
    const size_t XN = (size_t)Bb * Tt * Hh;
    const size_t HN = (size_t)Bb * Hh;

    for (int l = 0; l < 2; ++l) {
        const void* xsrc = (l == 0) ? p.input : (const void*)p.out;
        const size_t wOffG  = (size_t)l * Hh * G4H;
        const size_t bOffG  = (size_t)l * G4H;
        const size_t wOffAi = (size_t)l * Hh * Hh;
        const size_t wOffAo = (size_t)l * 2 * Hh * Hh;
        const size_t offH1  = XN + (size_t)l * HN;
        const size_t offC1  = XN + 2 * HN + (size_t)l * HN;
        const size_t offAtt = XN + 4 * HN;
        const int writeAtt = l;   // last layer only

        for (int t = 0; t < Tt; ++t) {
            const int last = (t == Tt - 1);

            { // ---- P1: gates -> hy, cy.  blocks = (bhalf 2) x (jg 128: 4 n-cols) ----
                const int bhf = bid >> 7;
                const int jg  = bid & 127;
                const int b0  = bhf << 4;
                float* xh = smem;                      // [16][1028] padded
                #pragma unroll
                for (int idx = tid; idx < 2048; idx += 512) {       // x rows (cached)
                    const int bb = idx >> 7, q = (idx & 127) << 2;
                    float4 v = ld4<F32>(xsrc, ((size_t)(b0 + bb) * Tt + t) * Hh + q);
                    float* dst = xh + bb * 1028 + q;
                    dst[0] = v.x; dst[1] = v.y; dst[2] = v.z; dst[3] = v.w;
                }
                if (t == 0) {
                    #pragma unroll
                    for (int idx = tid; idx < 2048; idx += 512) {   // h0 (cached, read-only)
                        const int bb = idx >> 7, q = (idx & 127) << 2;
                        float4 v = ld4<F32>(p.h0, (size_t)(b0 + bb) * Hh + q);
                        float* dst = xh + bb * 1028 + 512 + q;
                        dst[0] = v.x; dst[1] = v.y; dst[2] = v.z; dst[3] = v.w;
                    }
                } else {
                    #pragma unroll
                    for (int idx = tid; idx < 4096; idx += 512) {   // h carry (bypass)
                        const int bb = idx >> 8, q = (idx & 255) << 1;
                        float2 v = ldb2(p.h_ws + (size_t)(b0 + bb) * Hh + q);
                        float* dst = xh + bb * 1028 + 512 + q;
                        dst[0] = v.x; dst[1] = v.y;
                    }
                }
                __syncthreads();
                const int gq = tid & 3;            // gate 0..3
                const int bb = (tid >> 2) & 15;    // local b
                const int kq = tid >> 6;           // k chunk of 128 (0..7)
                const void* Wb = (kq < 4) ? p.Wi : p.Wh;
                const int kl = (kq & 3) * 128;     // local row within Wi or Wh
                size_t wi = wOffG + (size_t)kl * G4H + (size_t)(gq << 9) + (size_t)(jg << 2);
                const float* xrow = xh + bb * 1028 + kq * 128;
                float a0 = 0.f, a1 = 0.f, a2 = 0.f, a3 = 0.f;
                #pragma unroll 4
                for (int k = 0; k < 128; ++k) {
                    float4 w = ld4<F32>(Wb, wi);
                    float xv = xrow[k];
                    a0 += xv * w.x; a1 += xv * w.y; a2 += xv * w.z; a3 += xv * w.w;
                    wi += G4H;
                }
                float* red = smem + 16 * 1028;     // [8][16][17]
                const int rb = (kq * 16 + bb) * 17 + (gq << 2);
                red[rb] = a0; red[rb + 1] = a1; red[rb + 2] = a2; red[rb + 3] = a3;
                __syncthreads();
                float* ga = red + 8 * 16 * 17;     // [16][16]
                if (tid < 256) {
                    const int b2 = tid >> 4, jl = tid & 15;
                    float s = 0.f;
                    #pragma unroll
                    for (int q = 0; q < 8; ++q) s += red[(q * 16 + b2) * 17 + jl];
                    ga[(b2 << 4) + jl] = s;
                }
                __syncthreads();
                if (tid < 64) {
                    const int b2 = tid >> 2, nn = tid & 3;
                    const int b = b0 + b2, n = (jg << 2) + nn;
                    const int gb = (b2 << 4) + nn;
                    float gi = ga[gb]      + ldin<F32>(p.bi, bOffG + n)         + ldin<F32>(p.bhp, bOffG + n);
                    float gf = ga[gb + 4]  + ldin<F32>(p.bi, bOffG + 512 + n)   + ldin<F32>(p.bhp, bOffG + 512 + n);
                    float gg = ga[gb + 8]  + ldin<F32>(p.bi, bOffG + 1024 + n)  + ldin<F32>(p.bhp, bOffG + 1024 + n);
                    float go = ga[gb + 12] + ldin<F32>(p.bi, bOffG + 1536 + n)  + ldin<F32>(p.bhp, bOffG + 1536 + n);
                    float ig = 1.f / (1.f + __expf(-gi));
                    float fg = 1.f / (1.f + __expf(-gf));
                    float g2 = tanhf(gg);
                    float og = 1.f / (1.f + __expf(-go));
                    float cp = (t == 0) ? ldin<F32>(p.c0, (size_t)b * Hh + n)
                                        : ldb(p.c_ws + (size_t)b * Hh + n);
                    float cy = fg * cp + ig * g2;
                    float hy = og * tanhf(cy);
                    stb(p.c_ws  + (size_t)b * Hh + n, cy);
                    stb(p.hy_ws + (size_t)b * Hh + n, hy);
                    if (last) stout<F32>(p.out, offC1 + (size_t)b * Hh + n, cy);
                }
            }
            gbar(p.cnt, p.gen);

            { // ---- P2: target = hy @ Wa_in + zero wc/esum. blocks = (b 32) x (nc 8) ----
                const int b = bid >> 3, nc = bid & 7;
                float* hyL = smem;             // 512
                float* red = smem + 512;       // [64][9]
                hyL[tid] = ldb(p.hy_ws + (size_t)b * Hh + tid);
                if (nc == 0) {
                    stb(p.wc_ws + (size_t)b * Hh + tid, 0.f);
                    if (tid == 0) stb(p.esum_ws + b, 0.f);
                }
                __syncthreads();
                const int nl = tid & 63, kq = tid >> 6;
                const int n = (nc << 6) + nl;
                size_t wi = wOffAi + (size_t)(kq << 6) * Hh + n;
                float acc0 = 0.f, acc1 = 0.f;
                #pragma unroll 4
                for (int k = 0; k < 64; k += 2) {
                    acc0 += hyL[(kq << 6) + k]     * ldin<F32>(p.Wa_in, wi);
                    acc1 += hyL[(kq << 6) + k + 1] * ldin<F32>(p.Wa_in, wi + Hh);
                    wi += 2 * Hh;
                }
                red[nl * 9 + kq] = acc0 + acc1;
                __syncthreads();
                if (tid < 64) {
                    float s = 0.f;
                    #pragma unroll
                    for (int q = 0; q < 8; ++q) s += red[tid * 9 + q];
                    stb(p.tgt_ws + (size_t)b * Hh + (nc << 6) + tid, s);
                }
            }
            gbar(p.cnt, p.gen);

            { // ---- P3: scores + exp (no-max softmax) + wc partials. blocks = (b 32) x (sg 8) ----
                const int b = bid >> 3, sg = bid & 7;
                float* ctxL = smem;                    // [64][520]
                float* tgtL = smem + 64 * 520;         // 512
                float* eL   = tgtL + 512;              // 64
                #pragma unroll
                for (int idx = tid; idx < 8192; idx += 512) {       // ctx slice (L2-resident bf16)
                    const int r = idx >> 7, c4 = (idx & 127) << 2;
                    const size_t off = ((size_t)((sg << 6) + r) * Bb + b) * Hh + c4;
                    float4 v = p.ctxB16 ? ld4<false>(p.ctxs, off) : ld4<F32>(p.ctxs, off);
                    float* d = ctxL + r * 520 + c4;
                    d[0] = v.x; d[1] = v.y; d[2] = v.z; d[3] = v.w;
                }
                tgtL[tid] = ldb(p.tgt_ws + (size_t)b * Hh + tid);
                __syncthreads();
                const int r = tid >> 3, kq = tid & 7;  // strided-k: conflict-free
                const float* cr = ctxL + r * 520;
                float d0 = 0.f, d1 = 0.f;
                #pragma unroll 8
                for (int i = 0; i < 64; i += 2) {
                    const int k0 = kq + (i << 3), k1 = kq + ((i + 1) << 3);
                    d0 += cr[k0] * tgtL[k0];
                    d1 += cr[k1] * tgtL[k1];
                }
                float d = d0 + d1;
                d += __shfl_xor(d, 1); d += __shfl_xor(d, 2); d += __shfl_xor(d, 4);
                if (kq == 0) {
                    float e = __expf(d);               // bounded: |score| <~ 60, safe in fp32
                    eL[r] = e;
                    stb(p.e_ws + (size_t)b * Ss + (sg << 6) + r, e);
                }
                __syncthreads();
                if (tid < 64) {
                    float w = eL[tid];
                    #pragma unroll
                    for (int o = 32; o > 0; o >>= 1) w += __shfl_xor(w, o);
                    if (tid == 0) atomicAdd(p.esum_ws + b, w);
                }
                float acc0 = 0.f, acc1 = 0.f;
                #pragma unroll 8
                for (int rr = 0; rr < 64; rr += 2) {
                    acc0 += eL[rr]     * ctxL[rr * 520 + tid];
                    acc1 += eL[rr + 1] * ctxL[(rr + 1) * 520 + tid];
                }
                atomicAdd(p.wc_ws + (size_t)b * Hh + tid, acc0 + acc1);
            }
            gbar(p.cnt, p.gen);

            { // ---- P4: h_tilde = tanh([wc,hy]@Wa_out); x/h1/att writes. blocks = (b 32) x (nc 8) ----
                const int b = bid >> 3, nc = bid & 7;
                float* vL  = smem;           // 1024
                float* red = smem + 1024;    // [64][9]
                const float inv = 1.f / ldb(p.esum_ws + b);
                vL[tid]       = ldb(p.wc_ws + (size_t)b * Hh + tid) * inv;
                vL[512 + tid] = ldb(p.hy_ws + (size_t)b * Hh + tid);
                __syncthreads();
                const int nl = tid & 63, kq = tid >> 6;
                const int n = (nc << 6) + nl;
                size_t wi = wOffAo + (size_t)(kq << 7) * Hh + n;
                float acc0 = 0.f, acc1 = 0.f;
                #pragma unroll 4
                for (int k = 0; k < 128; k += 2) {
                    acc0 += vL[(kq << 7) + k]     * ldin<F32>(p.Wa_out, wi);
                    acc1 += vL[(kq << 7) + k + 1] * ldin<F32>(p.Wa_out, wi + Hh);
                    wi += 2 * Hh;
                }
                red[nl * 9 + kq] = acc0 + acc1;
                __syncthreads();
                if (tid < 64) {
                    float s = 0.f;
                    #pragma unroll
                    for (int q = 0; q < 8; ++q) s += red[tid * 9 + q];
                    float th = tanhf(s);
                    const int n2 = (nc << 6) + tid;
                    stb(p.h_ws + (size_t)b * Hh + n2, th);
                    stout<F32>(p.out, ((size_t)b * Tt + t) * Hh + n2, th);
                    if (last) stout<F32>(p.out, offH1 + (size_t)b * Hh + n2, th);
                }
                if (writeAtt && nc == 0) {
                    float pv = ldb(p.e_ws + (size_t)b * Ss + tid) * inv;
                    stout<F32>(p.out, offAtt + (size_t)tid * (Tt * Bb) + (size_t)t * Bb + b, pv);
                }
            }
            gbar(p.cnt, p.gen);
        }

        if (l == 0) {
            // heavy fence: flush dirty x rows (normal stores) so layer-1 blocks
            // on other XCDs read fresh data; invalidate stale clean lines.
            __threadfence();
            gbar(p.cnt, p.gen);
            __threadfence();
        }
    }
}

__global__ __launch_bounds__(512, 2) void kmain(KP p) {
    __shared__ float smem[SMEM_FLOATS];
    if (*p.flag) run_all<true >(p, smem);
    else         run_all<false>(p, smem);
}

// ===========================================================================
// Fallback path: original per-timestep kernels (proven correct)
// ===========================================================================
template<bool F32>
__device__ __forceinline__ void gates_body(
    const void* xsrc, const void* h0, const void* c0,
    const void* Wi, const void* bi, const void* Wh, const void* bh,
    size_t wOff, size_t bOff,
    const float* h_ws, float* c_ws, float* hy_ws,
    void* out, unsigned long long offC1, int t, int writeC1)
{
    __shared__ float xh[1024];
    __shared__ float red[4][32][8];
    __shared__ float ga[4][32];

    const int b  = blockIdx.x >> 4;
    const int jc = blockIdx.x & 15;
    const int tid = threadIdx.x;

    const size_t xrow = ((size_t)b * Tt + t) * Hh;
    for (int i = tid; i < 512; i += 256) xh[i] = ldin<F32>(xsrc, xrow + i);
    if (t == 0) {
        for (int i = tid; i < 512; i += 256) xh[512 + i] = ldin<F32>(h0, (size_t)b * Hh + i);
    } else {
        for (int i = tid; i < 512; i += 256) xh[512 + i] = h_ws[b * Hh + i];
    }
    __syncthreads();

    const int jl = tid & 31;
    const int kq = tid >> 5;
    const int j  = jc * 32 + jl;
    const void* Wbase = (kq < 4) ? Wi : Wh;
    const int k0 = (kq & 3) * 128;
    const int xoff = (kq < 4) ? 0 : 512;

    float a0 = 0.f, a1 = 0.f, a2 = 0.f, a3 = 0.f;
    size_t widx = wOff + (size_t)k0 * G4H + j;
    #pragma unroll 4
    for (int k = 0; k < 128; ++k) {
        float xv = xh[xoff + k0 + k];
        a0 += xv * ldin<F32>(Wbase, widx + 0 * Hh);
        a1 += xv * ldin<F32>(Wbase, widx + 1 * Hh);
        a2 += xv * ldin<F32>(Wbase, widx + 2 * Hh);
        a3 += xv * ldin<F32>(Wbase, widx + 3 * Hh);
        widx += G4H;
    }
    red[0][jl][kq] = a0; red[1][jl][kq] = a1;
    red[2][jl][kq] = a2; red[3][jl][kq] = a3;
    __syncthreads();

    if (tid < 128) {
        int g = tid >> 5, jj = tid & 31;
        float s = 0.f;
        #pragma unroll
        for (int q = 0; q < 8; ++q) s += red[g][jj][q];
        ga[g][jj] = s;
    }
    __syncthreads();

    if (tid < 32) {
        int jj = tid;
        int n = jc * 32 + jj;
        float gi = ga[0][jj] + ldin<F32>(bi, bOff + 0 * Hh + n) + ldin<F32>(bh, bOff + 0 * Hh + n);
        float gf = ga[1][jj] + ldin<F32>(bi, bOff + 1 * Hh + n) + ldin<F32>(bh, bOff + 1 * Hh + n);
        float gg = ga[2][jj] + ldin<F32>(bi, bOff + 2 * Hh + n) + ldin<F32>(bh, bOff + 2 * Hh + n);
        float go = ga[3][jj] + ldin<F32>(bi, bOff + 3 * Hh + n) + ldin<F32>(bh, bOff + 3 * Hh + n);
        float ig = 1.f / (1.f + __expf(-gi));
        float fg = 1.f / (1.f + __expf(-gf));
        float g2 = tanhf(gg);
        float og = 1.f / (1.f + __expf(-go));
        float cp = (t == 0) ? ldin<F32>(c0, (size_t)b * Hh + n) : c_ws[b * Hh + n];
        float cy = fg * cp + ig * g2;
        float hy = og * tanhf(cy);
        c_ws[b * Hh + n]  = cy;
        hy_ws[b * Hh + n] = hy;
        if (writeC1) stout<F32>(out, offC1 + (size_t)b * Hh + n, cy);
    }
}

__global__ __launch_bounds__(256) void k_gates(
    const int* flag, const void* xsrc, const void* h0, const void* c0,
    const void* Wi, const void* bi, const void* Wh, const void* bh,
    unsigned long long wOff, unsigned long long bOff,
    const float* h_ws, float* c_ws, float* hy_ws,
    void* out, unsigned long long offC1, int t, int writeC1)
{
    if (*flag) gates_body<true >(xsrc, h0, c0, Wi, bi, Wh, bh, wOff, bOff, h_ws, c_ws, hy_ws, out, offC1, t, writeC1);
    else       gates_body<false>(xsrc, h0, c0, Wi, bi, Wh, bh, wOff, bOff, h_ws, c_ws, hy_ws, out, offC1, t, writeC1);
}

template<bool F32>
__device__ __forceinline__ void target_body(
    const float* hy_ws, const void* Wa_in, size_t wOff, float* tgt_ws)
{
    __shared__ float hyL[512];
    __shared__ float red[64][4];

    const int b  = blockIdx.x >> 3;
    const int nc = blockIdx.x & 7;
    const int tid = threadIdx.x;

    for (int i = tid; i < 512; i += 256) hyL[i] = hy_ws[b * Hh + i];
    __syncthreads();

    const int nl = tid & 63;
    const int kq = tid >> 6;
    const int n  = nc * 64 + nl;
    const int kb = kq * 128;
    float acc = 0.f;
    #pragma unroll 4
    for (int k = 0; k < 128; ++k)
        acc += hyL[kb + k] * ldin<F32>(Wa_in, wOff + (size_t)(kb + k) * Hh + n);
    red[nl][kq] = acc;
    __syncthreads();

    if (tid < 64) {
        float s = red[tid][0] + red[tid][1] + red[tid][2] + red[tid][3];
        tgt_ws[b * Hh + nc * 64 + tid] = s;
    }
}

__global__ __launch_bounds__(256) void k_target(
    const int* flag, const float* hy_ws, const void* Wa_in,
    unsigned long long wOff, float* tgt_ws)
{
    if (*flag) target_body<true >(hy_ws, Wa_in, wOff, tgt_ws);
    else       target_body<false>(hy_ws, Wa_in, wOff, tgt_ws);
}

template<bool F32>
__device__ __forceinline__ void scores_body(
    const void* ctx, const float* tgt_ws, float* sc_ws)
{
    const int w    = threadIdx.x >> 6;
    const int lane = threadIdx.x & 63;
    const int id = blockIdx.x * 4 + w;
    const int b = id & 31;
    const int s = id >> 5;

    const size_t base = ((size_t)s * Bb + b) * Hh + lane * 8;
    const float* tp = tgt_ws + (size_t)b * Hh + lane * 8;
    float d = 0.f;
    #pragma unroll
    for (int i = 0; i < 8; ++i) d += ldin<F32>(ctx, base + i) * tp[i];
    #pragma unroll
    for (int o = 32; o > 0; o >>= 1) d += __shfl_xor(d, o);
    if (lane == 0) sc_ws[b * Ss + s] = d;
}

__global__ __launch_bounds__(256) void k_scores(
    const int* flag, const void* ctx, const float* tgt_ws, float* sc_ws)
{
    if (*flag) scores_body<true >(ctx, tgt_ws, sc_ws);
    else       scores_body<false>(ctx, tgt_ws, sc_ws);
}

template<bool F32>
__device__ __forceinline__ void wc_body(
    const void* ctx, const float* sc_ws, float* wc_ws,
    void* out, unsigned long long offAtt, int t, int writeAtt)
{
    __shared__ float scL[512];
    __shared__ float red[256];

    const int b   = blockIdx.x >> 2;
    const int hc  = blockIdx.x & 3;
    const int tid = threadIdx.x;

    scL[tid]       = sc_ws[b * Ss + tid];
    scL[tid + 256] = sc_ws[b * Ss + tid + 256];
    __syncthreads();

    red[tid] = fmaxf(scL[tid], scL[tid + 256]);
    __syncthreads();
    for (int o = 128; o > 0; o >>= 1) {
        if (tid < o) red[tid] = fmaxf(red[tid], red[tid + o]);
        __syncthreads();
    }
    const float M = red[0];
    __syncthreads();

    red[tid] = __expf(scL[tid] - M) + __expf(scL[tid + 256] - M);
    __syncthreads();
    for (int o = 128; o > 0; o >>= 1) {
        if (tid < o) red[tid] += red[tid + o];
        __syncthreads();
    }
    const float inv = 1.f / red[0];
    __syncthreads();

    const int h    = hc * 128 + (tid & 127);
    const int half = tid >> 7;
    float acc = 0.f;
    const int s0 = half * 256;
    for (int s = s0; s < s0 + 256; ++s)
        acc += __expf(scL[s] - M) * ldin<F32>(ctx, ((size_t)s * Bb + b) * Hh + h);

    red[tid] = acc;
    __syncthreads();
    if (half == 0)
        wc_ws[b * Hh + h] = (red[tid] + red[tid + 128]) * inv;

    if (writeAtt && hc == 0) {
        float p0 = __expf(scL[tid] - M) * inv;
        float p1 = __expf(scL[tid + 256] - M) * inv;
        stout<F32>(out, offAtt + (size_t)tid         * (Tt * Bb) + (size_t)t * Bb + b, p0);
        stout<F32>(out, offAtt + (size_t)(tid + 256) * (Tt * Bb) + (size_t)t * Bb + b, p1);
    }
}

__global__ __launch_bounds__(256) void k_wc(
    const int* flag, const void* ctx, const float* sc_ws, float* wc_ws,
    void* out, unsigned long long offAtt, int t, int writeAtt)
{
    if (*flag) wc_body<true >(ctx, sc_ws, wc_ws, out, offAtt, t, writeAtt);
    else       wc_body<false>(ctx, sc_ws, wc_ws, out, offAtt, t, writeAtt);
}

template<bool F32>
__device__ __forceinline__ void out_body(
    const float* hy_ws, const float* wc_ws, const void* Wa_out, size_t wOff,
    float* h_ws, void* out, unsigned long long offH1, int t, int writeH1)
{
    __shared__ float vL[1024];
    __shared__ float red[32][8];

    const int b  = blockIdx.x >> 4;
    const int nc = blockIdx.x & 15;
    const int tid = threadIdx.x;

    for (int h = tid; h < 512; h += 256) {
        vL[h]       = wc_ws[b * Hh + h];
        vL[512 + h] = hy_ws[b * Hh + h];
    }
    __syncthreads();

    const int nl = tid & 31;
    const int kq = tid >> 5;
    const int n  = nc * 32 + nl;
    const int kb = kq * 128;
    float acc = 0.f;
    #pragma unroll 4
    for (int k = 0; k < 128; ++k)
        acc += vL[kb + k] * ldin<F32>(Wa_out, wOff + (size_t)(kb + k) * Hh + n);
    red[nl][kq] = acc;
    __syncthreads();

    if (tid < 32) {
        float s = 0.f;
        #pragma unroll
        for (int q = 0; q < 8; ++q) s += red[tid][q];
        float th = tanhf(s);
        int n2 = nc * 32 + tid;
        h_ws[b * Hh + n2] = th;
        stout<F32>(out, ((size_t)b * Tt + t) * Hh + n2, th);
        if (writeH1) stout<F32>(out, offH1 + (size_t)b * Hh + n2, th);
    }
}

__global__ __launch_bounds__(256) void k_out(
    const int* flag, const float* hy_ws, const float* wc_ws, const void* Wa_out,
    unsigned long long wOff, float* h_ws, void* out,
    unsigned long long offH1, int t, int writeH1)
{
    if (*flag) out_body<true >(hy_ws, wc_ws, Wa_out, wOff, h_ws, out, offH1, t, writeH1);
    else       out_body<false>(hy_ws, wc_ws, Wa_out, wOff, h_ws, out, offH1, t, writeH1);
}

// ---------------------------------------------------------------------------
extern "C" void kernel_launch(void* const* d_in, const int* in_sizes, int n_in,
                              void* d_out, int out_size, void* d_ws, size_t ws_size,
                              hipStream_t stream)
{
    const void* input  = d_in[0];
    const void* h0     = d_in[1];
    const void* c0     = d_in[2];
    const void* ctx    = d_in[3];
    const void* Wi     = d_in[4];
    const void* bi     = d_in[5];
    const void* Wh     = d_in[6];
    const void* bh     = d_in[7];
    const void* Wa_in  = d_in[8];
    const void* Wa_out = d_in[9];

    const size_t XN = (size_t)Bb * Tt * Hh;
    const size_t HN = (size_t)Bb * Hh;
    const unsigned long long offH1base = XN;
    const unsigned long long offC1base = XN + 2 * HN;
    const unsigned long long offAtt    = XN + 4 * HN;

    int* flag = (int*)d_ws;
    int* cnt  = (int*)((char*)d_ws + 128);
    int* gen  = (int*)((char*)d_ws + 256);
    float* f  = (float*)((char*)d_ws + 512);
    float* h_ws    = f; f += HN;
    float* c_ws    = f; f += HN;
    float* hy_ws   = f; f += HN;
    float* tgt_ws  = f; f += HN;
    float* wc_ws   = f; f += HN;
    float* e_ws    = f; f += (size_t)Bb * Ss;
    float* sc_ws   = f; f += (size_t)Bb * Ss;   // fallback only
    float* esum_ws = f; f += 64;

    // ctx bf16 side-buffer (after the float workspace), guarded by ws_size
    const size_t CTXN = (size_t)Ss * Bb * Hh;                  // 8,388,608 elems
    size_t ctxbOff = 512 + ((char*)f - ((char*)d_ws + 512));
    ctxbOff = (ctxbOff + 255) & ~(size_t)255;
    const int useB16 = (ws_size >= ctxbOff + CTXN * sizeof(u16)) ? 1 : 0;
    u16* ctxb = (u16*)((char*)d_ws + ctxbOff);

    k_detect<<<dim3(1), dim3(256), 0, stream>>>(ctx, flag, cnt, gen);
    if (useB16)
        k_cvt<<<dim3((unsigned)(CTXN / 8 / 256)), dim3(256), 0, stream>>>(flag, ctx, ctxb);

    KP hp;
    hp.input = input; hp.h0 = h0; hp.c0 = c0; hp.ctx = ctx;
    hp.Wi = Wi; hp.bi = bi; hp.Wh = Wh; hp.bhp = bh;
    hp.Wa_in = Wa_in; hp.Wa_out = Wa_out;
    hp.ctxs = useB16 ? (const void*)ctxb : ctx;
    hp.ctxB16 = useB16;
    hp.out = d_out; hp.flag = flag;
    hp.cnt = cnt; hp.gen = gen;
    hp.h_ws = h_ws; hp.c_ws = c_ws; hp.hy_ws = hy_ws; hp.tgt_ws = tgt_ws;
    hp.wc_ws = wc_ws; hp.e_ws = e_ws; hp.esum_ws = esum_ws;

    void* kargs[] = { &hp };
    hipError_t err = hipLaunchCooperativeKernel(kmain, dim3(NBLK), dim3(512), kargs, 0u, stream);

    if (err != hipSuccess) {
        (void)hipGetLastError();   // clear error state
        // Fallback: proven per-timestep multi-kernel path
        for (int l = 0; l < 2; ++l) {
            const void* xsrc = (l == 0) ? input : (const void*)d_out;
            const unsigned long long wOffG  = (unsigned long long)l * Hh * G4H;
            const unsigned long long bOffG  = (unsigned long long)l * G4H;
            const unsigned long long wOffAi = (unsigned long long)l * Hh * Hh;
            const unsigned long long wOffAo = (unsigned long long)l * 2 * Hh * Hh;
            const unsigned long long offH1  = offH1base + (unsigned long long)l * HN;
            const unsigned long long offC1  = offC1base + (unsigned long long)l * HN;

            for (int t = 0; t < Tt; ++t) {
                const int last = (t == Tt - 1) ? 1 : 0;
                k_gates<<<dim3(512), dim3(256), 0, stream>>>(
                    flag, xsrc, h0, c0, Wi, bi, Wh, bh, wOffG, bOffG,
                    h_ws, c_ws, hy_ws, d_out, offC1, t, last);
                k_target<<<dim3(256), dim3(256), 0, stream>>>(
                    flag, hy_ws, Wa_in, wOffAi, tgt_ws);
                k_scores<<<dim3(4096), dim3(256), 0, stream>>>(
                    flag, ctx, tgt_ws, sc_ws);
                k_wc<<<dim3(128), dim3(256), 0, stream>>>(
                    flag, ctx, sc_ws, wc_ws, d_out, offAtt, t, l);
                k_out<<<dim3(512), dim3(256), 0, stream>>>(
                    flag, hy_ws, wc_ws, Wa_out, wOffAo, h_ws, d_out, offH1, t, last);
            }
        }
    }
}

// Round 4
// 19654.379 us; speedup vs baseline: 1.9022x; 1.9022x over previous
//
#include <hip/hip_runtime.h>

typedef unsigned short u16;
typedef unsigned int   u32;
typedef unsigned long long u64;

#define Bb   32
#define Tt   256
#define Ss   512
#define Hh   512
#define G4H  2048
#define NBLK 256

// ---- dtype-polymorphic load/store: F32 ? fp32 : bf16 ------------------------
template<bool F32>
__device__ __forceinline__ float ldin(const void* p, size_t i) {
    if constexpr (F32) {
        return ((const float*)p)[i];
    } else {
        u32 v = ((u32)((const u16*)p)[i]) << 16;
        return __uint_as_float(v);
    }
}
template<bool F32>
__device__ __forceinline__ void stout(void* p, size_t i, float f) {
    if constexpr (F32) {
        ((float*)p)[i] = f;
    } else {
        u32 x = __float_as_uint(f);
        u32 r = x + 0x7fffu + ((x >> 16) & 1u);   // RNE
        ((u16*)p)[i] = (u16)(r >> 16);
    }
}
template<bool F32>
__device__ __forceinline__ float4 ld4(const void* p, size_t i) {
    if constexpr (F32) {
        return *(const float4*)((const float*)p + i);
    } else {
        ushort4 u = *(const ushort4*)((const u16*)p + i);
        float4 f;
        f.x = __uint_as_float((u32)u.x << 16);
        f.y = __uint_as_float((u32)u.y << 16);
        f.z = __uint_as_float((u32)u.z << 16);
        f.w = __uint_as_float((u32)u.w << 16);
        return f;
    }
}
__device__ __forceinline__ u32 pack2bf(float a, float b) {
    u32 xa = __float_as_uint(a), xb = __float_as_uint(b);
    u32 ra = (xa + 0x7fffu + ((xa >> 16) & 1u)) >> 16;
    u32 rb = (xb + 0x7fffu + ((xb >> 16) & 1u)) & 0xffff0000u;
    return ra | rb;
}

// ---- cache-bypassing (coherence-point) accessors for mutable ws state -------
__device__ __forceinline__ float ldb(const float* p) {
    return __hip_atomic_load(p, __ATOMIC_RELAXED, __HIP_MEMORY_SCOPE_AGENT);
}
__device__ __forceinline__ void stb(float* p, float v) {
    __hip_atomic_store(p, v, __ATOMIC_RELAXED, __HIP_MEMORY_SCOPE_AGENT);
}
__device__ __forceinline__ float2 ldb2(const float* p) {
    u64 v = __hip_atomic_load((const u64*)p, __ATOMIC_RELAXED, __HIP_MEMORY_SCOPE_AGENT);
    float2 r;
    r.x = __uint_as_float((u32)v);
    r.y = __uint_as_float((u32)(v >> 32));
    return r;
}

// ---- 2-level tree barrier: 16 leaves x 16 blocks + root, relaxed atomics ----
// bars layout (128B-strided int slots): [0..15] leafcnt, [16..31] leafgen,
// [32] rootcnt, [33] rootgen
__device__ __forceinline__ void gbar2(int* bars, int expected) {
    __syncthreads();
    if (threadIdx.x == 0) {
        const int leaf = blockIdx.x >> 4;
        int* lc = bars + leaf * 32;
        int* lg = bars + (16 + leaf) * 32;
        int* rc = bars + 32 * 32;
        int* rg = bars + 33 * 32;
        if (__hip_atomic_fetch_add(lc, 1, __ATOMIC_RELAXED, __HIP_MEMORY_SCOPE_AGENT) == 15) {
            asm volatile("s_waitcnt vmcnt(0)" ::: "memory");
            if (__hip_atomic_fetch_add(rc, 1, __ATOMIC_RELAXED, __HIP_MEMORY_SCOPE_AGENT) == 15) {
                __hip_atomic_store(rc, 0, __ATOMIC_RELAXED, __HIP_MEMORY_SCOPE_AGENT);
                asm volatile("s_waitcnt vmcnt(0)" ::: "memory");
                __hip_atomic_store(rg, expected, __ATOMIC_RELAXED, __HIP_MEMORY_SCOPE_AGENT);
            } else {
                while (__hip_atomic_load(rg, __ATOMIC_RELAXED, __HIP_MEMORY_SCOPE_AGENT) < expected)
                    __builtin_amdgcn_s_sleep(1);
            }
            __hip_atomic_store(lc, 0, __ATOMIC_RELAXED, __HIP_MEMORY_SCOPE_AGENT);
            asm volatile("s_waitcnt vmcnt(0)" ::: "memory");
            __hip_atomic_store(lg, expected, __ATOMIC_RELAXED, __HIP_MEMORY_SCOPE_AGENT);
        } else {
            while (__hip_atomic_load(lg, __ATOMIC_RELAXED, __HIP_MEMORY_SCOPE_AGENT) < expected)
                __builtin_amdgcn_s_sleep(1);
        }
    }
    __syncthreads();
}

// ---------------------------------------------------------------------------
// K0: dtype detector + barrier-state init
// ---------------------------------------------------------------------------
__global__ __launch_bounds__(256) void k_detect(const void* ctx, int* flag, int* bars) {
    __shared__ int c_sh;
    if (threadIdx.x == 0) c_sh = 0;
    __syncthreads();
    const u16* p = (const u16*)ctx;
    int c = 0;
    for (int i = threadIdx.x; i < 16384; i += 256) {
        int e = (p[i] >> 7) & 0xFF;
        if (e >= 0xC8) c++;
    }
    atomicAdd(&c_sh, c);
    __syncthreads();
    if (threadIdx.x == 0) *flag = (c_sh > 64) ? 1 : 0;
    if (threadIdx.x < 34) bars[threadIdx.x * 32] = 0;
}

// ===========================================================================
// Fused persistent kernel: 256 blocks x 512 threads
//  - ctx slice resident in LDS (bf16-packed, skewed) for the whole run
//  - P1/P2/P4 use 8-b-broadcast weight blocks (weights fully L2-resident)
//  - tree grid barrier
// ===========================================================================
struct KP {
    const void *input, *h0, *c0, *ctx, *Wi, *bi, *Wh, *bhp, *Wa_in, *Wa_out;
    void* out;
    const int* flag;
    int* bars;
    float *h_ws, *c_ws, *hy_ws, *tgt_ws, *wc_ws, *e_ws, *esum_ws;
};

// LDS: [0..16895] ctxU (64 rows x 264 u32, skewed bf16 pairs)
//      [16896..27439] phase scratch (max 10544: P1 xh 8200 + red 2080 + ga 264)
//      [27440..27503] cL (block-local LSTM cell state)
#define CTXU_FLOATS 16896
#define SCR_FLOATS  10544
#define SMEM_FLOATS (CTXU_FLOATS + SCR_FLOATS + 64)

template<bool F32>
__device__ void run_all(const KP& p, float* smem) {
    const int bid = blockIdx.x;
    const int tid = threadIdx.x;
    const size_t XN = (size_t)Bb * Tt * Hh;
    const size_t HN = (size_t)Bb * Hh;
    u32*   ctxU = (u32*)smem;
    float* S    = smem + CTXU_FLOATS;
    float* cL   = smem + CTXU_FLOATS + SCR_FLOATS;
    int ep = 0;

    // ---- one-time: stage this block's ctx slice into LDS (bf16-packed, skewed)
    {
        const int b = bid >> 3, sg = bid & 7;
        for (int idx = tid; idx < 8192; idx += 512) {      // 64 rows x 128 float4
            const int r = idx >> 7, q4 = (idx & 127) << 2;
            float4 v = ld4<F32>(p.ctx, ((size_t)((sg << 6) + r) * Bb + b) * Hh + q4);
            const int w = q4 >> 1;                          // even word index
            const int sk = w >> 5;
            ctxU[r * 264 + w + sk]     = pack2bf(v.x, v.y);
            ctxU[r * 264 + w + 1 + sk] = pack2bf(v.z, v.w);
        }
    }
    __syncthreads();

    for (int l = 0; l < 2; ++l) {
        const void* xsrc = (l == 0) ? p.input : (const void*)p.out;
        const size_t wOffG  = (size_t)l * Hh * G4H;
        const size_t bOffG  = (size_t)l * G4H;
        const size_t wOffAi = (size_t)l * Hh * Hh;
        const size_t wOffAo = (size_t)l * 2 * Hh * Hh;
        const size_t offH1  = XN + (size_t)l * HN;
        const size_t offC1  = XN + 2 * HN + (size_t)l * HN;
        const size_t offAtt = XN + 4 * HN;
        const int writeAtt = l;

        for (int t = 0; t < Tt; ++t) {
            const int last = (t == Tt - 1);

            { // ---- P1: gates -> hy, cy.  blocks = (bq 4: 8 b's) x (colg 64: 8 n) ----
                const int bq = bid >> 6, colg = bid & 63;
                const int b0 = bq << 3;
                float* xh  = S;                 // [8][1025]
                float* red = S + 8200;          // [4][520]
                float* ga  = S + 10280;         // [8][33]
                for (int idx = tid; idx < 1024; idx += 512) {
                    const int bb = idx >> 7, q = (idx & 127) << 2;
                    float4 v = ld4<F32>(xsrc, ((size_t)(b0 + bb) * Tt + t) * Hh + q);
                    float* d = xh + bb * 1025 + q;
                    d[0] = v.x; d[1] = v.y; d[2] = v.z; d[3] = v.w;
                }
                if (t == 0) {
                    for (int idx = tid; idx < 1024; idx += 512) {
                        const int bb = idx >> 7, q = (idx & 127) << 2;
                        float4 v = ld4<F32>(p.h0, (size_t)(b0 + bb) * Hh + q);
                        float* d = xh + bb * 1025 + 512 + q;
                        d[0] = v.x; d[1] = v.y; d[2] = v.z; d[3] = v.w;
                    }
                } else {
                    for (int idx = tid; idx < 2048; idx += 512) {
                        const int bb = idx >> 8, q = (idx & 255) << 1;
                        float2 v = ldb2(p.h_ws + (size_t)(b0 + bb) * Hh + q);
                        float* d = xh + bb * 1025 + 512 + q;
                        d[0] = v.x; d[1] = v.y;
                    }
                }
                __syncthreads();
                const int kq = tid >> 6, cq = (tid >> 3) & 7, b8 = tid & 7;
                const int gq = cq >> 1, j4 = (cq & 1) << 2;
                const int col = (gq << 9) + (colg << 3) + j4;
                const void* Wb = (kq < 4) ? p.Wi : p.Wh;
                size_t wi = wOffG + ((size_t)((kq & 3) << 7)) * G4H + col;
                const float* xr = xh + b8 * 1025 + (kq << 7);
                float a0 = 0.f, a1 = 0.f, a2 = 0.f, a3 = 0.f;
                #pragma unroll 16
                for (int k = 0; k < 128; ++k) {
                    float4 w = ld4<F32>(Wb, wi);
                    float xv = xr[k];
                    a0 += xv * w.x; a1 += xv * w.y; a2 += xv * w.z; a3 += xv * w.w;
                    wi += G4H;
                }
                red[0 * 520 + tid] = a0; red[1 * 520 + tid] = a1;
                red[2 * 520 + tid] = a2; red[3 * 520 + tid] = a3;
                __syncthreads();
                if (tid < 256) {
                    const int rb8 = tid >> 5, cl = tid & 31;
                    const int rcq = cl >> 2, rc = cl & 3;
                    float s = 0.f;
                    #pragma unroll
                    for (int q = 0; q < 8; ++q) s += red[rc * 520 + (q << 6) + (rcq << 3) + rb8];
                    ga[rb8 * 33 + cl] = s;
                }
                __syncthreads();
                if (tid < 64) {
                    const int b8i = tid >> 3, nn = tid & 7;
                    const int b = b0 + b8i, n = (colg << 3) + nn;
                    float gi = ga[b8i * 33 + nn]      + ldin<F32>(p.bi, bOffG + n)        + ldin<F32>(p.bhp, bOffG + n);
                    float gf = ga[b8i * 33 + 8 + nn]  + ldin<F32>(p.bi, bOffG + 512 + n)  + ldin<F32>(p.bhp, bOffG + 512 + n);
                    float gg = ga[b8i * 33 + 16 + nn] + ldin<F32>(p.bi, bOffG + 1024 + n) + ldin<F32>(p.bhp, bOffG + 1024 + n);
                    float go = ga[b8i * 33 + 24 + nn] + ldin<F32>(p.bi, bOffG + 1536 + n) + ldin<F32>(p.bhp, bOffG + 1536 + n);
                    float ig = 1.f / (1.f + __expf(-gi));
                    float fg = 1.f / (1.f + __expf(-gf));
                    float g2 = tanhf(gg);
                    float og = 1.f / (1.f + __expf(-go));
                    float cp = (t == 0) ? ldin<F32>(p.c0, (size_t)b * Hh + n) : cL[tid];
                    float cy = fg * cp + ig * g2;
                    float hy = og * tanhf(cy);
                    cL[tid] = cy;
                    stb(p.hy_ws + (size_t)b * Hh + n, hy);
                    if (last) stout<F32>(p.out, offC1 + (size_t)b * Hh + n, cy);
                }
            }
            ++ep; gbar2(p.bars, ep);

            { // ---- P2: tgt = hy @ Wa_in. blocks = (bq 4) x (colg 64: 8 cols) ----
                const int bq = bid >> 6, colg = bid & 63;
                const int b0 = bq << 3;
                float* hyL = S;                 // [8][513]
                float* red = S + 4104;          // [4][520]
                for (int idx = tid; idx < 2048; idx += 512) {
                    const int bb = idx >> 8, q = (idx & 255) << 1;
                    float2 v = ldb2(p.hy_ws + (size_t)(b0 + bb) * Hh + q);
                    hyL[bb * 513 + q] = v.x; hyL[bb * 513 + q + 1] = v.y;
                }
                if (colg == 0) {
                    for (int idx = tid; idx < 4096; idx += 512)
                        stb(p.wc_ws + (size_t)(b0 + (idx >> 9)) * Hh + (idx & 511), 0.f);
                    if (tid < 8) stb(p.esum_ws + b0 + tid, 0.f);
                }
                __syncthreads();
                const int kq = tid >> 4, cq = (tid >> 3) & 1, b8 = tid & 7;
                const int col = (colg << 3) + (cq << 2);
                size_t wi = wOffAi + ((size_t)(kq << 4)) * Hh + col;
                const float* hr = hyL + b8 * 513 + (kq << 4);
                float a0 = 0.f, a1 = 0.f, a2 = 0.f, a3 = 0.f;
                #pragma unroll
                for (int k = 0; k < 16; ++k) {
                    float4 w = ld4<F32>(p.Wa_in, wi);
                    float xv = hr[k];
                    a0 += xv * w.x; a1 += xv * w.y; a2 += xv * w.z; a3 += xv * w.w;
                    wi += Hh;
                }
                red[0 * 520 + tid] = a0; red[1 * 520 + tid] = a1;
                red[2 * 520 + tid] = a2; red[3 * 520 + tid] = a3;
                __syncthreads();
                if (tid < 64) {
                    const int b8i = tid >> 3, cl = tid & 7;
                    const int rcq = cl >> 2, rc = cl & 3;
                    float s = 0.f;
                    #pragma unroll
                    for (int q = 0; q < 32; ++q) s += red[rc * 520 + (q << 4) + (rcq << 3) + b8i];
                    stb(p.tgt_ws + (size_t)(b0 + b8i) * Hh + (colg << 3) + cl, s);
                }
            }
            ++ep; gbar2(p.bars, ep);

            { // ---- P3: scores + exp + wc partials, ctx from LDS. blocks = (b 32) x (sg 8) ----
                const int b = bid >> 3, sg = bid & 7;
                float* tgtL = S;                // 512
                float* eL   = S + 512;          // 64
                tgtL[tid] = ldb(p.tgt_ws + (size_t)b * Hh + tid);
                __syncthreads();
                const int r = tid >> 3, kq = tid & 7;
                const u32* cw = ctxU + r * 264 + kq * 33;
                const float* tp = tgtL + (kq << 6);
                float d = 0.f;
                #pragma unroll 8
                for (int j = 0; j < 32; ++j) {
                    u32 u = cw[j];
                    d += __uint_as_float(u << 16)          * tp[2 * j]
                       + __uint_as_float(u & 0xffff0000u)  * tp[2 * j + 1];
                }
                d += __shfl_xor(d, 1); d += __shfl_xor(d, 2); d += __shfl_xor(d, 4);
                if (kq == 0) {
                    float e = __expf(d);            // bounded: |score| <~ 60, safe in fp32
                    eL[r] = e;
                    stb(p.e_ws + (size_t)b * Ss + (sg << 6) + r, e);
                }
                __syncthreads();
                if (tid < 64) {
                    float w = eL[tid];
                    #pragma unroll
                    for (int o = 32; o > 0; o >>= 1) w += __shfl_xor(w, o);
                    if (tid == 0) atomicAdd(p.esum_ws + b, w);
                }
                const int wd = tid >> 1, hodd = tid & 1;
                const int woff = wd + (wd >> 5);
                float acc = 0.f;
                #pragma unroll 8
                for (int rr = 0; rr < 64; ++rr) {
                    u32 u = ctxU[rr * 264 + woff];
                    float v = hodd ? __uint_as_float(u & 0xffff0000u) : __uint_as_float(u << 16);
                    acc += eL[rr] * v;
                }
                atomicAdd(p.wc_ws + (size_t)b * Hh + tid, acc);
            }
            ++ep; gbar2(p.bars, ep);

            { // ---- P4: h~ = tanh([wc,hy]@Wa_out). blocks = (bq 4) x (colg 64: 8 cols) ----
                const int bq = bid >> 6, colg = bid & 63;
                const int b0 = bq << 3;
                float* vL   = S;                // [8][1025]
                float* red  = S + 8200;         // [4][520]
                float* invL = S + 10280;        // [8]
                if (tid < 8) invL[tid] = 1.f / ldb(p.esum_ws + b0 + tid);
                __syncthreads();
                for (int idx = tid; idx < 2048; idx += 512) {
                    const int bb = idx >> 8, q = (idx & 255) << 1;
                    float2 v = ldb2(p.wc_ws + (size_t)(b0 + bb) * Hh + q);
                    const float iv = invL[bb];
                    vL[bb * 1025 + q] = v.x * iv; vL[bb * 1025 + q + 1] = v.y * iv;
                }
                for (int idx = tid; idx < 2048; idx += 512) {
                    const int bb = idx >> 8, q = (idx & 255) << 1;
                    float2 v = ldb2(p.hy_ws + (size_t)(b0 + bb) * Hh + q);
                    vL[bb * 1025 + 512 + q] = v.x; vL[bb * 1025 + 512 + q + 1] = v.y;
                }
                __syncthreads();
                const int kq = tid >> 4, cq = (tid >> 3) & 1, b8 = tid & 7;
                const int col = (colg << 3) + (cq << 2);
                size_t wi = wOffAo + ((size_t)(kq << 5)) * Hh + col;
                const float* vr = vL + b8 * 1025 + (kq << 5);
                float a0 = 0.f, a1 = 0.f, a2 = 0.f, a3 = 0.f;
                #pragma unroll 8
                for (int k = 0; k < 32; ++k) {
                    float4 w = ld4<F32>(p.Wa_out, wi);
                    float xv = vr[k];
                    a0 += xv * w.x; a1 += xv * w.y; a2 += xv * w.z; a3 += xv * w.w;
                    wi += Hh;
                }
                red[0 * 520 + tid] = a0; red[1 * 520 + tid] = a1;
                red[2 * 520 + tid] = a2; red[3 * 520 + tid] = a3;
                __syncthreads();
                if (tid < 64) {
                    const int b8i = tid >> 3, cl = tid & 7;
                    const int rcq = cl >> 2, rc = cl & 3;
                    float s = 0.f;
                    #pragma unroll
                    for (int q = 0; q < 32; ++q) s += red[rc * 520 + (q << 4) + (rcq << 3) + b8i];
                    float th = tanhf(s);
                    const int b = b0 + b8i, n2 = (colg << 3) + cl;
                    stb(p.h_ws + (size_t)b * Hh + n2, th);
                    stout<F32>(p.out, ((size_t)b * Tt + t) * Hh + n2, th);
                    if (last) stout<F32>(p.out, offH1 + (size_t)b * Hh + n2, th);
                }
                if (writeAtt && colg < 8) {
                    const int b8a = tid >> 6, si = tid & 63;
                    const int s = (colg << 6) + si;
                    float pv = ldb(p.e_ws + (size_t)(b0 + b8a) * Ss + s) * invL[b8a];
                    stout<F32>(p.out, offAtt + (size_t)s * (Tt * Bb) + (size_t)t * Bb + (b0 + b8a), pv);
                }
            }
            ++ep; gbar2(p.bars, ep);
        }

        if (l == 0) {
            // heavy fence: flush dirty x rows (normal stores) across XCDs
            __threadfence();
            ++ep; gbar2(p.bars, ep);
            __threadfence();
        }
    }
}

__global__ __launch_bounds__(512, 2) void kmain(KP p) {
    __shared__ float smem[SMEM_FLOATS];
    if (*p.flag) run_all<true >(p, smem);
    else         run_all<false>(p, smem);
}

// ===========================================================================
// Fallback path: original per-timestep kernels (proven correct)
// ===========================================================================
template<bool F32>
__device__ __forceinline__ void gates_body(
    const void* xsrc, const void* h0, const void* c0,
    const void* Wi, const void* bi, const void* Wh, const void* bh,
    size_t wOff, size_t bOff,
    const float* h_ws, float* c_ws, float* hy_ws,
    void* out, unsigned long long offC1, int t, int writeC1)
{
    __shared__ float xh[1024];
    __shared__ float red[4][32][8];
    __shared__ float ga[4][32];

    const int b  = blockIdx.x >> 4;
    const int jc = blockIdx.x & 15;
    const int tid = threadIdx.x;

    const size_t xrow = ((size_t)b * Tt + t) * Hh;
    for (int i = tid; i < 512; i += 256) xh[i] = ldin<F32>(xsrc, xrow + i);
    if (t == 0) {
        for (int i = tid; i < 512; i += 256) xh[512 + i] = ldin<F32>(h0, (size_t)b * Hh + i);
    } else {
        for (int i = tid; i < 512; i += 256) xh[512 + i] = h_ws[b * Hh + i];
    }
    __syncthreads();

    const int jl = tid & 31;
    const int kq = tid >> 5;
    const int j  = jc * 32 + jl;
    const void* Wbase = (kq < 4) ? Wi : Wh;
    const int k0 = (kq & 3) * 128;
    const int xoff = (kq < 4) ? 0 : 512;

    float a0 = 0.f, a1 = 0.f, a2 = 0.f, a3 = 0.f;
    size_t widx = wOff + (size_t)k0 * G4H + j;
    #pragma unroll 4
    for (int k = 0; k < 128; ++k) {
        float xv = xh[xoff + k0 + k];
        a0 += xv * ldin<F32>(Wbase, widx + 0 * Hh);
        a1 += xv * ldin<F32>(Wbase, widx + 1 * Hh);
        a2 += xv * ldin<F32>(Wbase, widx + 2 * Hh);
        a3 += xv * ldin<F32>(Wbase, widx + 3 * Hh);
        widx += G4H;
    }
    red[0][jl][kq] = a0; red[1][jl][kq] = a1;
    red[2][jl][kq] = a2; red[3][jl][kq] = a3;
    __syncthreads();

    if (tid < 128) {
        int g = tid >> 5, jj = tid & 31;
        float s = 0.f;
        #pragma unroll
        for (int q = 0; q < 8; ++q) s += red[g][jj][q];
        ga[g][jj] = s;
    }
    __syncthreads();

    if (tid < 32) {
        int jj = tid;
        int n = jc * 32 + jj;
        float gi = ga[0][jj] + ldin<F32>(bi, bOff + 0 * Hh + n) + ldin<F32>(bh, bOff + 0 * Hh + n);
        float gf = ga[1][jj] + ldin<F32>(bi, bOff + 1 * Hh + n) + ldin<F32>(bh, bOff + 1 * Hh + n);
        float gg = ga[2][jj] + ldin<F32>(bi, bOff + 2 * Hh + n) + ldin<F32>(bh, bOff + 2 * Hh + n);
        float go = ga[3][jj] + ldin<F32>(bi, bOff + 3 * Hh + n) + ldin<F32>(bh, bOff + 3 * Hh + n);
        float ig = 1.f / (1.f + __expf(-gi));
        float fg = 1.f / (1.f + __expf(-gf));
        float g2 = tanhf(gg);
        float og = 1.f / (1.f + __expf(-go));
        float cp = (t == 0) ? ldin<F32>(c0, (size_t)b * Hh + n) : c_ws[b * Hh + n];
        float cy = fg * cp + ig * g2;
        float hy = og * tanhf(cy);
        c_ws[b * Hh + n]  = cy;
        hy_ws[b * Hh + n] = hy;
        if (writeC1) stout<F32>(out, offC1 + (size_t)b * Hh + n, cy);
    }
}

__global__ __launch_bounds__(256) void k_gates(
    const int* flag, const void* xsrc, const void* h0, const void* c0,
    const void* Wi, const void* bi, const void* Wh, const void* bh,
    unsigned long long wOff, unsigned long long bOff,
    const float* h_ws, float* c_ws, float* hy_ws,
    void* out, unsigned long long offC1, int t, int writeC1)
{
    if (*flag) gates_body<true >(xsrc, h0, c0, Wi, bi, Wh, bh, wOff, bOff, h_ws, c_ws, hy_ws, out, offC1, t, writeC1);
    else       gates_body<false>(xsrc, h0, c0, Wi, bi, Wh, bh, wOff, bOff, h_ws, c_ws, hy_ws, out, offC1, t, writeC1);
}

template<bool F32>
__device__ __forceinline__ void target_body(
    const float* hy_ws, const void* Wa_in, size_t wOff, float* tgt_ws)
{
    __shared__ float hyL[512];
    __shared__ float red[64][4];

    const int b  = blockIdx.x >> 3;
    const int nc = blockIdx.x & 7;
    const int tid = threadIdx.x;

    for (int i = tid; i < 512; i += 256) hyL[i] = hy_ws[b * Hh + i];
    __syncthreads();

    const int nl = tid & 63;
    const int kq = tid >> 6;
    const int n  = nc * 64 + nl;
    const int kb = kq * 128;
    float acc = 0.f;
    #pragma unroll 4
    for (int k = 0; k < 128; ++k)
        acc += hyL[kb + k] * ldin<F32>(Wa_in, wOff + (size_t)(kb + k) * Hh + n);
    red[nl][kq] = acc;
    __syncthreads();

    if (tid < 64) {
        float s = red[tid][0] + red[tid][1] + red[tid][2] + red[tid][3];
        tgt_ws[b * Hh + nc * 64 + tid] = s;
    }
}

__global__ __launch_bounds__(256) void k_target(
    const int* flag, const float* hy_ws, const void* Wa_in,
    unsigned long long wOff, float* tgt_ws)
{
    if (*flag) target_body<true >(hy_ws, Wa_in, wOff, tgt_ws);
    else       target_body<false>(hy_ws, Wa_in, wOff, tgt_ws);
}

template<bool F32>
__device__ __forceinline__ void scores_body(
    const void* ctx, const float* tgt_ws, float* sc_ws)
{
    const int w    = threadIdx.x >> 6;
    const int lane = threadIdx.x & 63;
    const int id = blockIdx.x * 4 + w;
    const int b = id & 31;
    const int s = id >> 5;

    const size_t base = ((size_t)s * Bb + b) * Hh + lane * 8;
    const float* tp = tgt_ws + (size_t)b * Hh + lane * 8;
    float d = 0.f;
    #pragma unroll
    for (int i = 0; i < 8; ++i) d += ldin<F32>(ctx, base + i) * tp[i];
    #pragma unroll
    for (int o = 32; o > 0; o >>= 1) d += __shfl_xor(d, o);
    if (lane == 0) sc_ws[b * Ss + s] = d;
}

__global__ __launch_bounds__(256) void k_scores(
    const int* flag, const void* ctx, const float* tgt_ws, float* sc_ws)
{
    if (*flag) scores_body<true >(ctx, tgt_ws, sc_ws);
    else       scores_body<false>(ctx, tgt_ws, sc_ws);
}

template<bool F32>
__device__ __forceinline__ void wc_body(
    const void* ctx, const float* sc_ws, float* wc_ws,
    void* out, unsigned long long offAtt, int t, int writeAtt)
{
    __shared__ float scL[512];
    __shared__ float red[256];

    const int b   = blockIdx.x >> 2;
    const int hc  = blockIdx.x & 3;
    const int tid = threadIdx.x;

    scL[tid]       = sc_ws[b * Ss + tid];
    scL[tid + 256] = sc_ws[b * Ss + tid + 256];
    __syncthreads();

    red[tid] = fmaxf(scL[tid], scL[tid + 256]);
    __syncthreads();
    for (int o = 128; o > 0; o >>= 1) {
        if (tid < o) red[tid] = fmaxf(red[tid], red[tid + o]);
        __syncthreads();
    }
    const float M = red[0];
    __syncthreads();

    red[tid] = __expf(scL[tid] - M) + __expf(scL[tid + 256] - M);
    __syncthreads();
    for (int o = 128; o > 0; o >>= 1) {
        if (tid < o) red[tid] += red[tid + o];
        __syncthreads();
    }
    const float inv = 1.f / red[0];
    __syncthreads();

    const int h    = hc * 128 + (tid & 127);
    const int half = tid >> 7;
    float acc = 0.f;
    const int s0 = half * 256;
    for (int s = s0; s < s0 + 256; ++s)
        acc += __expf(scL[s] - M) * ldin<F32>(ctx, ((size_t)s * Bb + b) * Hh + h);

    red[tid] = acc;
    __syncthreads();
    if (half == 0)
        wc_ws[b * Hh + h] = (red[tid] + red[tid + 128]) * inv;

    if (writeAtt && hc == 0) {
        float p0 = __expf(scL[tid] - M) * inv;
        float p1 = __expf(scL[tid + 256] - M) * inv;
        stout<F32>(out, offAtt + (size_t)tid         * (Tt * Bb) + (size_t)t * Bb + b, p0);
        stout<F32>(out, offAtt + (size_t)(tid + 256) * (Tt * Bb) + (size_t)t * Bb + b, p1);
    }
}

__global__ __launch_bounds__(256) void k_wc(
    const int* flag, const void* ctx, const float* sc_ws, float* wc_ws,
    void* out, unsigned long long offAtt, int t, int writeAtt)
{
    if (*flag) wc_body<true >(ctx, sc_ws, wc_ws, out, offAtt, t, writeAtt);
    else       wc_body<false>(ctx, sc_ws, wc_ws, out, offAtt, t, writeAtt);
}

template<bool F32>
__device__ __forceinline__ void out_body(
    const float* hy_ws, const float* wc_ws, const void* Wa_out, size_t wOff,
    float* h_ws, void* out, unsigned long long offH1, int t, int writeH1)
{
    __shared__ float vL[1024];
    __shared__ float red[32][8];

    const int b  = blockIdx.x >> 4;
    const int nc = blockIdx.x & 15;
    const int tid = threadIdx.x;

    for (int h = tid; h < 512; h += 256) {
        vL[h]       = wc_ws[b * Hh + h];
        vL[512 + h] = hy_ws[b * Hh + h];
    }
    __syncthreads();

    const int nl = tid & 31;
    const int kq = tid >> 5;
    const int n  = nc * 32 + nl;
    const int kb = kq * 128;
    float acc = 0.f;
    #pragma unroll 4
    for (int k = 0; k < 128; ++k)
        acc += vL[kb + k] * ldin<F32>(Wa_out, wOff + (size_t)(kb + k) * Hh + n);
    red[nl][kq] = acc;
    __syncthreads();

    if (tid < 32) {
        float s = 0.f;
        #pragma unroll
        for (int q = 0; q < 8; ++q) s += red[tid][q];
        float th = tanhf(s);
        int n2 = nc * 32 + tid;
        h_ws[b * Hh + n2] = th;
        stout<F32>(out, ((size_t)b * Tt + t) * Hh + n2, th);
        if (writeH1) stout<F32>(out, offH1 + (size_t)b * Hh + n2, th);
    }
}

__global__ __launch_bounds__(256) void k_out(
    const int* flag, const float* hy_ws, const float* wc_ws, const void* Wa_out,
    unsigned long long wOff, float* h_ws, void* out,
    unsigned long long offH1, int t, int writeH1)
{
    if (*flag) out_body<true >(hy_ws, wc_ws, Wa_out, wOff, h_ws, out, offH1, t, writeH1);
    else       out_body<false>(hy_ws, wc_ws, Wa_out, wOff, h_ws, out, offH1, t, writeH1);
}

// ---------------------------------------------------------------------------
extern "C" void kernel_launch(void* const* d_in, const int* in_sizes, int n_in,
                              void* d_out, int out_size, void* d_ws, size_t ws_size,
                              hipStream_t stream)
{
    const void* input  = d_in[0];
    const void* h0     = d_in[1];
    const void* c0     = d_in[2];
    const void* ctx    = d_in[3];
    const void* Wi     = d_in[4];
    const void* bi     = d_in[5];
    const void* Wh     = d_in[6];
    const void* bh     = d_in[7];
    const void* Wa_in  = d_in[8];
    const void* Wa_out = d_in[9];

    const size_t XN = (size_t)Bb * Tt * Hh;
    const size_t HN = (size_t)Bb * Hh;
    const unsigned long long offH1base = XN;
    const unsigned long long offC1base = XN + 2 * HN;
    const unsigned long long offAtt    = XN + 4 * HN;

    int* flag = (int*)d_ws;
    int* bars = (int*)((char*)d_ws + 128);             // 34 slots x 128 B
    float* f  = (float*)((char*)d_ws + 128 + 34 * 128);
    float* h_ws    = f; f += HN;
    float* c_ws    = f; f += HN;
    float* hy_ws   = f; f += HN;
    float* tgt_ws  = f; f += HN;
    float* wc_ws   = f; f += HN;
    float* e_ws    = f; f += (size_t)Bb * Ss;
    float* sc_ws   = f; f += (size_t)Bb * Ss;          // fallback only
    float* esum_ws = f; f += 64;

    k_detect<<<dim3(1), dim3(256), 0, stream>>>(ctx, flag, bars);

    KP hp;
    hp.input = input; hp.h0 = h0; hp.c0 = c0; hp.ctx = ctx;
    hp.Wi = Wi; hp.bi = bi; hp.Wh = Wh; hp.bhp = bh;
    hp.Wa_in = Wa_in; hp.Wa_out = Wa_out;
    hp.out = d_out; hp.flag = flag; hp.bars = bars;
    hp.h_ws = h_ws; hp.c_ws = c_ws; hp.hy_ws = hy_ws; hp.tgt_ws = tgt_ws;
    hp.wc_ws = wc_ws; hp.e_ws = e_ws; hp.esum_ws = esum_ws;

    void* kargs[] = { &hp };
    hipError_t err = hipLaunchCooperativeKernel(kmain, dim3(NBLK), dim3(512), kargs, 0u, stream);

    if (err != hipSuccess) {
        (void)hipGetLastError();   // clear error state
        // Fallback: proven per-timestep multi-kernel path
        for (int l = 0; l < 2; ++l) {
            const void* xsrc = (l == 0) ? input : (const void*)d_out;
            const unsigned long long wOffG  = (unsigned long long)l * Hh * G4H;
            const unsigned long long bOffG  = (unsigned long long)l * G4H;
            const unsigned long long wOffAi = (unsigned long long)l * Hh * Hh;
            const unsigned long long wOffAo = (unsigned long long)l * 2 * Hh * Hh;
            const unsigned long long offH1  = offH1base + (unsigned long long)l * HN;
            const unsigned long long offC1  = offC1base + (unsigned long long)l * HN;

            for (int t = 0; t < Tt; ++t) {
                const int last = (t == Tt - 1) ? 1 : 0;
                k_gates<<<dim3(512), dim3(256), 0, stream>>>(
                    flag, xsrc, h0, c0, Wi, bi, Wh, bh, wOffG, bOffG,
                    h_ws, c_ws, hy_ws, d_out, offC1, t, last);
                k_target<<<dim3(256), dim3(256), 0, stream>>>(
                    flag, hy_ws, Wa_in, wOffAi, tgt_ws);
                k_scores<<<dim3(4096), dim3(256), 0, stream>>>(
                    flag, ctx, tgt_ws, sc_ws);
                k_wc<<<dim3(128), dim3(256), 0, stream>>>(
                    flag, ctx, sc_ws, wc_ws, d_out, offAtt, t, l);
                k_out<<<dim3(512), dim3(256), 0, stream>>>(
                    flag, hy_ws, wc_ws, Wa_out, wOffAo, h_ws, d_out, offH1, t, last);
            }
        }
    }
}